// Round 7
// baseline (719.097 us; speedup 1.0000x reference)
//
#include <hip/hip_runtime.h>

// ---------------------------------------------------------------------------
// SAGAN self-attention block, MI355X / gfx950.
// B=4, C=256, H=W=64 (HW=4096), Ck=32.
// v7: 4-way split-K flash attention (4 independent blocks/CU, 32 waves/CU),
// 4-way merge kernel.  k_sigma/k_proj unchanged from v6.
// ---------------------------------------------------------------------------

constexpr int kC   = 256;
constexpr int kHW  = 4096;
constexpr int kB   = 4;
constexpr int kCHW = kC * kHW;

typedef short bf16x8 __attribute__((ext_vector_type(8)));
typedef float f32x4  __attribute__((ext_vector_type(4)));
typedef unsigned short u16;

__device__ __forceinline__ u16 f2bf(float f) {
    union { float f; unsigned u; } v; v.f = f;
    unsigned u = v.u;
    return (u16)((u + 0x7fffu + ((u >> 16) & 1u)) >> 16);  // RNE
}
__device__ __forceinline__ float bf2f(u16 h) {
    union { unsigned u; float f; } v; v.u = ((unsigned)h) << 16;
    return v.f;
}

// ---------------------------------------------------------------------------
// Kernel 1: inverse spectral norms + W -> bf16 hi/lo in MFMA-A-fragment-
// packed order: idx = R*4096 + s*512 + l15*32 + k  (R = co>>4, l15 = co&15,
// s = ci>>5, k = ci&31).  Rows: [0,32)=fw, [32,64)=gw, [64,320)=hww.
// ---------------------------------------------------------------------------
__global__ __launch_bounds__(1024) void k_sigma(
    const float* __restrict__ fw, const float* __restrict__ fu,
    const float* __restrict__ gw, const float* __restrict__ gu,
    const float* __restrict__ hww, const float* __restrict__ hu,
    float* __restrict__ sig, u16* __restrict__ wh, u16* __restrict__ wl)
{
    const int which = blockIdx.x;
    const float* W = which == 0 ? fw : (which == 1 ? gw : hww);
    const float* U = which == 0 ? fu : (which == 1 ? gu : hu);
    const int O = (which == 2) ? 256 : 32;
    const int t = threadIdx.x;

    __shared__ float par[4][256];
    __shared__ float red[256];
    __shared__ __align__(16) float Vv[256];

    {
        const int i = t & 255, och = t >> 8;
        int olim = O - och * 64; olim = olim < 0 ? 0 : (olim > 64 ? 64 : olim);
        float p = 0.f;
        for (int oo = 0; oo < olim; ++oo) {
            const int o = och * 64 + oo;
            p += U[o] * W[o * 256 + i];
        }
        par[och][i] = p;
    }
    __syncthreads();
    float t1 = 0.f;
    if (t < 256) {
        t1 = par[0][t] + par[1][t] + par[2][t] + par[3][t];
        red[t] = t1 * t1;
    }
    __syncthreads();
    for (int s = 128; s > 0; s >>= 1) { if (t < s) red[t] += red[t + s]; __syncthreads(); }
    if (t < 256) Vv[t] = t1 / fmaxf(sqrtf(red[0]), 1e-12f);
    __syncthreads();

    {
        const int o = t & 255, ich = t >> 8;
        float q = 0.f;
        if (o < O) {
            const float4* Wr = (const float4*)(W + (size_t)o * 256 + ich * 64);
            const float4* Vr = (const float4*)(&Vv[ich * 64]);
#pragma unroll
            for (int j = 0; j < 16; ++j) {
                const float4 w = Wr[j]; const float4 v = Vr[j];
                q += w.x * v.x + w.y * v.y + w.z * v.z + w.w * v.w;
            }
        }
        par[ich][o] = q;
    }
    __syncthreads();
    if (t < 256) {
        const float t2 = par[0][t] + par[1][t] + par[2][t] + par[3][t];
        red[t] = t2 * t2;
    }
    __syncthreads();
    for (int s = 128; s > 0; s >>= 1) { if (t < s) red[t] += red[t + s]; __syncthreads(); }
    if (t == 0) {
        const float s2 = red[0];
        sig[which] = fmaxf(sqrtf(s2), 1e-12f) / s2;   // 1/sigma
    }

    // ---- W -> bf16 hi/lo, A-fragment-packed ----
    const int nElem = O * 256;
    const int gbase = (which == 0) ? 0 : (which == 1 ? 32 : 64);  // row base
    for (int i = t; i < nElem; i += 1024) {
        const int o = i >> 8, ci = i & 255;
        const int g = gbase + o;
        const int idx = ((g >> 4) * 8 + (ci >> 5)) * 512 + (g & 15) * 32 + (ci & 31);
        const float f = W[i];
        const u16 h = f2bf(f);
        wh[idx] = h;
        wl[idx] = f2bf(f - bf2f(h));
    }
}

// ---------------------------------------------------------------------------
// Kernel 2: all projections as one MFMA GEMM.  grid (64 n-tiles, 4 b),
// 512 thr (8 waves).  Wave = (nch = wave&3, cohalf = wave>>2).
// A-operands (weights) loaded from fragment-packed global: 1 KB/instr,
// fully coalesced.  x staged fp32 via global_load_lds, column-gathered
// into hi/lo B-frags.  3 MFMAs per K-chunk (wl*xl dropped).
// ---------------------------------------------------------------------------
__global__ __launch_bounds__(512) void k_proj(
    const float* __restrict__ x,
    const u16* __restrict__ wh, const u16* __restrict__ wl,
    const float* __restrict__ fb, const float* __restrict__ gb,
    const float* __restrict__ hb, const float* __restrict__ sig,
    u16* __restrict__ Kc, u16* __restrict__ Qc, u16* __restrict__ Vb)
{
    __shared__ __align__(16) float xs[256][64];  // 64 KB
    __shared__ float bLDS[320];

    const int t = threadIdx.x;
    const int wave = t >> 6, lane = t & 63;
    const int quad = lane >> 4, l15 = lane & 15;
    const int b = blockIdx.y;
    const int n0 = blockIdx.x * 64;
    const int nch = wave & 3, cohalf = wave >> 2;

    // stage x tile [256 ci][64 n]
    {
        const int r4i = lane >> 4, c16 = lane & 15;
        const float* xg = x + (size_t)b * kCHW + (size_t)r4i * kHW + n0 + c16 * 4;
#pragma unroll
        for (int j = 0; j < 8; ++j) {
            const int cibase = (wave * 8 + j) * 4;
            __builtin_amdgcn_global_load_lds(
                (const __attribute__((address_space(1))) void*)(xg + (size_t)cibase * kHW),
                (__attribute__((address_space(3))) void*)&xs[cibase][0], 16, 0, 0);
        }
    }
    if (t < 320) bLDS[t] = (t < 32) ? fb[t] : (t < 64) ? gb[t - 32] : hb[t - 64];
    __syncthreads();

    // B-frags (x) hi/lo for 8 ci-slices; lane = col n
    const int n = nch * 16 + l15;
    bf16x8 bh[8], bl[8];
#pragma unroll
    for (int s = 0; s < 8; ++s) {
        union { u16 a[8]; bf16x8 v; } H, L;
#pragma unroll
        for (int j = 0; j < 8; ++j) {
            const float v = xs[s * 32 + quad * 8 + j][n];
            const u16 h = f2bf(v);
            H.a[j] = h; L.a[j] = f2bf(v - bf2f(h));
        }
        bh[s] = H.v; bl[s] = L.v;
    }

    // A-frag lane base into packed layout
    const u16* whp = wh + l15 * 32 + quad * 8;
    const u16* wlp = wl + l15 * 32 + quad * 8;

    f32x4 acc[10] = {};
#pragma unroll
    for (int c = 0; c < 10; ++c) {
        const size_t base = (size_t)(cohalf * 10 + c) * 4096;
#pragma unroll
        for (int s = 0; s < 8; ++s) {
            const bf16x8 ah = *(const bf16x8*)(whp + base + s * 512);
            const bf16x8 al = *(const bf16x8*)(wlp + base + s * 512);
            acc[c] = __builtin_amdgcn_mfma_f32_16x16x32_bf16(ah, bh[s], acc[c], 0, 0, 0);
            acc[c] = __builtin_amdgcn_mfma_f32_16x16x32_bf16(ah, bl[s], acc[c], 0, 0, 0);
            acc[c] = __builtin_amdgcn_mfma_f32_16x16x32_bf16(al, bh[s], acc[c], 0, 0, 0);
        }
    }

    const float s0 = sig[0], s1 = sig[1], s2 = sig[2];
#pragma unroll
    for (int c = 0; c < 10; ++c) {
        const int cog0 = (cohalf * 10 + c) * 16;
        const float inv = (cog0 < 32) ? s0 : (cog0 < 64) ? s1 : s2;
#pragma unroll
        for (int r = 0; r < 4; ++r) {
            const int co = cog0 + quad * 4 + r;
            const float v = acc[c][r] * inv + bLDS[co];
            if (co < 64) {
                u16* H = (co < 32) ? Kc : Qc;
                const int d = co & 31;
                const u16 h = f2bf(v);
                const u16 l = f2bf(v - bf2f(h));
                const size_t off = (size_t)(b * kHW + n0 + n) * 64;
                H[off + d] = h;
                H[off + 32 + d] = l;
            } else {
                Vb[((size_t)b * kC + (co - 64)) * kHW + n0 + n] = f2bf(v);
            }
        }
    }
}

// ---------------------------------------------------------------------------
// Kernel 3: flash attention v7, 4-way split-K.  grid 1024 (XCD-swizzled;
// id>>8 = key-quarter), 512 thr (8 waves) -> 4 independent blocks/CU
// (VGPR capped at 64 via launch_bounds, LDS 25.5 KB -> 4 x fits).
// Per block: 64 rows x 1024 keys (16 tiles).
// ---------------------------------------------------------------------------
__global__ __launch_bounds__(512, 8) void k_attn(
    const u16* __restrict__ Kc, const u16* __restrict__ Qc,
    const u16* __restrict__ Vb,
    u16* __restrict__ Op, float2* __restrict__ St)
{
    __shared__ __align__(16) u16 Qt[2][4096];   // 16 KB
    __shared__ __align__(16) u16 Pt[4096];      // 8 KB
    __shared__ float2 stLDS[8][16];
    __shared__ float aLDS[64];

    const int t = threadIdx.x;
    const int wave = t >> 6, lane = t & 63;
    const int quad = lane >> 4, l15 = lane & 15;
    const int sg = wave >> 1, half = wave & 1;

    const int id = blockIdx.x;
    const int xcd = id & 7;
    const int b = xcd >> 1;
    const int nb0 = ((xcd & 1) * 32 + ((id >> 3) & 31)) * 64;
    const int mh = id >> 8;                    // key-quarter (0..3)
    const int mt0 = mh * 16, mt1 = mt0 + 16;

    const u16* Kb  = Kc + (size_t)b * kHW * 64;
    const u16* Qb  = Qc + (size_t)b * kHW * 64;
    const u16* Vbb = Vb + (size_t)b * kC * kHW;

    const size_t krow = (size_t)(nb0 + sg * 16 + l15) * 64 + (size_t)quad * 8;
    const bf16x8 kh = *(const bf16x8*)(Kb + krow);
    const bf16x8 kl = *(const bf16x8*)(Kb + krow + 32);

    const u16* vrow[2];
#pragma unroll
    for (int ct = 0; ct < 2; ++ct)
        vrow[ct] = Vbb + (size_t)(wave * 32 + ct * 16 + l15) * kHW + quad * 8;

    const int qs_row = lane >> 3, qs_ch = lane & 7;

    f32x4 O[8] = {};
    float mrow = -1e30f, lrow = 0.f;
    bf16x8 vc[4], vn[4];

    // ---- prologue ----
    {
        const int rloc = wave * 8 + qs_row;
        __builtin_amdgcn_global_load_lds(
            (const __attribute__((address_space(1))) void*)
                (Qb + (size_t)(mt0 * 64 + rloc) * 64 + ((qs_ch ^ (rloc & 7)) << 3)),
            (__attribute__((address_space(3))) void*)&Qt[0][wave * 512], 16, 0, 0);
    }
#pragma unroll
    for (int ct = 0; ct < 2; ++ct)
#pragma unroll
        for (int ks = 0; ks < 2; ++ks)
            vc[ct * 2 + ks] = *(const bf16x8*)(vrow[ct] + mt0 * 64 + ks * 32);

    for (int mt = mt0; mt < mt1; ++mt) {
        const int cur = mt & 1;
        const int m0 = mt * 64;

        __syncthreads();   // B1: Qt[cur] ready

        if (mt < mt1 - 1) {
            const int m0n = m0 + 64;
            const int rloc = wave * 8 + qs_row;
            __builtin_amdgcn_global_load_lds(
                (const __attribute__((address_space(1))) void*)
                    (Qb + (size_t)(m0n + rloc) * 64 + ((qs_ch ^ (rloc & 7)) << 3)),
                (__attribute__((address_space(3))) void*)&Qt[cur ^ 1][wave * 512], 16, 0, 0);
        }
        const int m0v = (mt < mt1 - 1) ? m0 + 64 : m0;
#pragma unroll
        for (int ct = 0; ct < 2; ++ct)
#pragma unroll
            for (int ks = 0; ks < 2; ++ks)
                vn[ct * 2 + ks] = *(const bf16x8*)(vrow[ct] + m0v + ks * 32);

        // ---- scores for this wave's m-half ----
        f32x4 s[2];
#pragma unroll
        for (int mi2 = 0; mi2 < 2; ++mi2) {
            const int mi = half * 2 + mi2;
            const int rbase = (mi * 16 + l15) * 64;
            const bf16x8 qhv = *(const bf16x8*)&Qt[cur][rbase + ((quad       ^ (l15 & 7)) << 3)];
            const bf16x8 qlv = *(const bf16x8*)&Qt[cur][rbase + (((quad + 4) ^ (l15 & 7)) << 3)];
            f32x4 a = { 0.f, 0.f, 0.f, 0.f };
            a = __builtin_amdgcn_mfma_f32_16x16x32_bf16(qhv, kl, a, 0, 0, 0);
            a = __builtin_amdgcn_mfma_f32_16x16x32_bf16(qlv, kh, a, 0, 0, 0);
            a = __builtin_amdgcn_mfma_f32_16x16x32_bf16(qhv, kh, a, 0, 0, 0);
            s[mi2] = a;
        }

        // ---- wave-local stats ----
        float lm = s[0][0];
#pragma unroll
        for (int mi2 = 0; mi2 < 2; ++mi2)
#pragma unroll
            for (int r = 0; r < 4; ++r) lm = fmaxf(lm, s[mi2][r]);
        lm = fmaxf(lm, __shfl_xor(lm, 16));
        lm = fmaxf(lm, __shfl_xor(lm, 32));
        float ls = 0.f;
#pragma unroll
        for (int mi2 = 0; mi2 < 2; ++mi2)
#pragma unroll
            for (int r = 0; r < 4; ++r) {
                const float p = __expf(s[mi2][r] - lm);
                s[mi2][r] = p;
                ls += p;
            }
        ls += __shfl_xor(ls, 16);
        ls += __shfl_xor(ls, 32);
        if (lane < 16) stLDS[wave][l15] = make_float2(lm, ls);

        asm volatile("s_waitcnt lgkmcnt(0)\n\ts_barrier" ::: "memory");  // Bstat

        const float2 o2 = stLDS[wave ^ 1][l15];
        const float mnew = fmaxf(mrow, fmaxf(lm, o2.x));
        const float alpha = __expf(mrow - mnew);
        const float bm = __expf(lm - mnew);
        lrow = lrow * alpha + ls * bm + o2.y * __expf(o2.x - mnew);
        mrow = mnew;

        // ---- pack P (scaled by bm), write alpha ----
        {
            const int prow = sg * 16 + l15;
#pragma unroll
            for (int mi2 = 0; mi2 < 2; ++mi2) {
                const float p0 = s[mi2][0] * bm, p1 = s[mi2][1] * bm;
                const float p2 = s[mi2][2] * bm, p3 = s[mi2][3] * bm;
                const unsigned d0 = __builtin_amdgcn_perm(
                    __float_as_uint(p1), __float_as_uint(p0), 0x07060302u);
                const unsigned d1 = __builtin_amdgcn_perm(
                    __float_as_uint(p3), __float_as_uint(p2), 0x07060302u);
                const int mi = half * 2 + mi2;
                const int chunk = 2 * mi + (quad >> 1);
                const int off = prow * 64 + ((chunk ^ (l15 & 7)) << 3) + (quad & 1) * 4;
                *(uint2*)(Pt + off) = make_uint2(d0, d1);
            }
            if (half == 0 && lane < 16) aLDS[sg * 16 + l15] = alpha;
        }

        asm volatile("s_waitcnt lgkmcnt(0)\n\ts_barrier" ::: "memory");  // BP

        // ---- rescale O ----
#pragma unroll
        for (int rg = 0; rg < 4; ++rg) {
            const float4 af = *(const float4*)&aLDS[rg * 16 + quad * 4];
#pragma unroll
            for (int ct = 0; ct < 2; ++ct) {
                O[rg * 2 + ct][0] *= af.x;
                O[rg * 2 + ct][1] *= af.y;
                O[rg * 2 + ct][2] *= af.z;
                O[rg * 2 + ct][3] *= af.w;
            }
        }

        // ---- PV ----
#pragma unroll
        for (int ks = 0; ks < 2; ++ks) {
#pragma unroll
            for (int rg = 0; rg < 4; ++rg) {
                const bf16x8 pa = *(const bf16x8*)&Pt[(rg * 16 + l15) * 64
                                     + (((ks * 4 + quad) ^ (l15 & 7)) << 3)];
#pragma unroll
                for (int ct = 0; ct < 2; ++ct)
                    O[rg * 2 + ct] = __builtin_amdgcn_mfma_f32_16x16x32_bf16(
                        pa, vc[ct * 2 + ks], O[rg * 2 + ct], 0, 0, 0);
            }
        }

#pragma unroll
        for (int i = 0; i < 4; ++i) vc[i] = vn[i];
    }

    // ---- epilogue: bf16 partial O + stats ----
    if (half == 0 && lane < 16)
        St[(size_t)(mh * 4 + b) * kHW + nb0 + sg * 16 + l15] = make_float2(mrow, lrow);

    u16* Opb = Op + (size_t)(mh * 4 + b) * kHW * 256;
#pragma unroll
    for (int rg = 0; rg < 4; ++rg) {
#pragma unroll
        for (int ct = 0; ct < 2; ++ct) {
#pragma unroll
            for (int r = 0; r < 4; ++r) {
                const int nn = nb0 + rg * 16 + quad * 4 + r;
                const int c = wave * 32 + ct * 16 + l15;
                Opb[(size_t)nn * 256 + c] = f2bf(O[rg * 2 + ct][r]);
            }
        }
    }
}

// ---------------------------------------------------------------------------
// Kernel 4: merge the four key-quarters + epilogue.  grid 2048 x 256 thr,
// 8 channels per thread, fully coalesced.
// ---------------------------------------------------------------------------
__global__ __launch_bounds__(256) void k_merge(
    const float* __restrict__ x, const float* __restrict__ gamma,
    const u16* __restrict__ Op, const float2* __restrict__ St,
    float* __restrict__ out)
{
    const int tid = blockIdx.x * 256 + threadIdx.x;
    const int cg = tid & 31;
    const int n  = (tid >> 5) & 4095;
    const int b  = tid >> 17;
    const int c0 = cg * 8;

    float2 st[4];
#pragma unroll
    for (int q = 0; q < 4; ++q) st[q] = St[(size_t)(q * 4 + b) * kHW + n];
    float M = st[0].x;
#pragma unroll
    for (int q = 1; q < 4; ++q) M = fmaxf(M, st[q].x);
    float w[4], L = 0.f;
#pragma unroll
    for (int q = 0; q < 4; ++q) { w[q] = __expf(st[q].x - M); L += st[q].y * w[q]; }
    const float invL = 1.f / L;
#pragma unroll
    for (int q = 0; q < 4; ++q) w[q] *= invL;
    const float g = gamma[0];

    const size_t base = ((size_t)b * kHW + n) * 256 + c0;
    uint4 A[4];
#pragma unroll
    for (int q = 0; q < 4; ++q)
        A[q] = *(const uint4*)(Op + base + (size_t)q * 4 * kHW * 256);
    const float4 x0 = *(const float4*)(x + base);
    const float4 x1 = *(const float4*)(x + base + 4);

    float o[8];
#pragma unroll
    for (int j = 0; j < 8; ++j) {
        const unsigned w0 = (j >> 1 == 0) ? 0u : 0u;  // (index helper below)
        float acc = 0.f;
#pragma unroll
        for (int q = 0; q < 4; ++q) {
            const unsigned word = (j >> 1) == 0 ? A[q].x : (j >> 1) == 1 ? A[q].y
                                 : (j >> 1) == 2 ? A[q].z : A[q].w;
            acc += bf2f((u16)(word >> ((j & 1) * 16))) * w[q];
        }
        o[j] = acc;
        (void)w0;
    }
    float4 r0, r1;
    r0.x = g * o[0] + x0.x; r0.y = g * o[1] + x0.y;
    r0.z = g * o[2] + x0.z; r0.w = g * o[3] + x0.w;
    r1.x = g * o[4] + x1.x; r1.y = g * o[5] + x1.y;
    r1.z = g * o[6] + x1.z; r1.w = g * o[7] + x1.w;
    *(float4*)(out + base)     = r0;
    *(float4*)(out + base + 4) = r1;
}

// ---------------------------------------------------------------------------
extern "C" void kernel_launch(void* const* d_in, const int* in_sizes, int n_in,
                              void* d_out, int out_size, void* d_ws, size_t ws_size,
                              hipStream_t stream)
{
    const float* x     = (const float*)d_in[0];
    const float* fw    = (const float*)d_in[1];
    const float* fb    = (const float*)d_in[2];
    const float* fu    = (const float*)d_in[3];
    const float* gw    = (const float*)d_in[4];
    const float* gb    = (const float*)d_in[5];
    const float* gu    = (const float*)d_in[6];
    const float* hww   = (const float*)d_in[7];
    const float* hb    = (const float*)d_in[8];
    const float* hu    = (const float*)d_in[9];
    const float* gamma = (const float*)d_in[10];
    float* out = (float*)d_out;

    char* ws = (char*)d_ws;
    float* sig = (float*)ws;                        // 3 floats
    u16* wh = (u16*)(ws + 1024);                    // packed 320x256 bf16 hi
    u16* wl = wh + 320 * 256;                       // packed lo
    u16* Kc = (u16*)(ws + (1u << 20));              // 2 MB
    u16* Qc = (u16*)(ws + (3u << 20));              // 2 MB
    u16* Vb = (u16*)(ws + (5u << 20));              // 8 MB
    u16* Op = (u16*)(ws + (16u << 20));             // 32 MB: [4][4][4096][256] bf16
    float2* St = (float2*)(ws + (48u << 20));       // 512 KB: [4][4][4096]

    k_sigma<<<dim3(3), dim3(1024), 0, stream>>>(fw, fu, gw, gu, hww, hu, sig, wh, wl);
    k_proj<<<dim3(64, 4), dim3(512), 0, stream>>>(x, wh, wl, fb, gb, hb, sig,
                                                  Kc, Qc, Vb);
    k_attn<<<dim3(1024), dim3(512), 0, stream>>>(Kc, Qc, Vb, Op, St);
    k_merge<<<dim3(2048), dim3(256), 0, stream>>>(x, gamma, Op, St, out);
}

// Round 8
// 260.800 us; speedup vs baseline: 2.7573x; 2.7573x over previous
//
#include <hip/hip_runtime.h>

// ---------------------------------------------------------------------------
// SAGAN self-attention block, MI355X / gfx950.
// B=4, C=256, H=W=64 (HW=4096), Ck=32.
// v8: v7's 4-way split-K flash attention with the register cliff fixed:
// __launch_bounds__(512,4) keeps VGPR=64 (no spill); HW reaches 4 blocks/CU
// on its own since 64 VGPR supports 8 waves/SIMD.
// ---------------------------------------------------------------------------

constexpr int kC   = 256;
constexpr int kHW  = 4096;
constexpr int kB   = 4;
constexpr int kCHW = kC * kHW;

typedef short bf16x8 __attribute__((ext_vector_type(8)));
typedef float f32x4  __attribute__((ext_vector_type(4)));
typedef unsigned short u16;

__device__ __forceinline__ u16 f2bf(float f) {
    union { float f; unsigned u; } v; v.f = f;
    unsigned u = v.u;
    return (u16)((u + 0x7fffu + ((u >> 16) & 1u)) >> 16);  // RNE
}
__device__ __forceinline__ float bf2f(u16 h) {
    union { unsigned u; float f; } v; v.u = ((unsigned)h) << 16;
    return v.f;
}

// ---------------------------------------------------------------------------
// Kernel 1: inverse spectral norms + W -> bf16 hi/lo in MFMA-A-fragment-
// packed order: idx = R*4096 + s*512 + l15*32 + k  (R = co>>4, l15 = co&15,
// s = ci>>5, k = ci&31).  Rows: [0,32)=fw, [32,64)=gw, [64,320)=hww.
// ---------------------------------------------------------------------------
__global__ __launch_bounds__(1024) void k_sigma(
    const float* __restrict__ fw, const float* __restrict__ fu,
    const float* __restrict__ gw, const float* __restrict__ gu,
    const float* __restrict__ hww, const float* __restrict__ hu,
    float* __restrict__ sig, u16* __restrict__ wh, u16* __restrict__ wl)
{
    const int which = blockIdx.x;
    const float* W = which == 0 ? fw : (which == 1 ? gw : hww);
    const float* U = which == 0 ? fu : (which == 1 ? gu : hu);
    const int O = (which == 2) ? 256 : 32;
    const int t = threadIdx.x;

    __shared__ float par[4][256];
    __shared__ float red[256];
    __shared__ __align__(16) float Vv[256];

    {
        const int i = t & 255, och = t >> 8;
        int olim = O - och * 64; olim = olim < 0 ? 0 : (olim > 64 ? 64 : olim);
        float p = 0.f;
        for (int oo = 0; oo < olim; ++oo) {
            const int o = och * 64 + oo;
            p += U[o] * W[o * 256 + i];
        }
        par[och][i] = p;
    }
    __syncthreads();
    float t1 = 0.f;
    if (t < 256) {
        t1 = par[0][t] + par[1][t] + par[2][t] + par[3][t];
        red[t] = t1 * t1;
    }
    __syncthreads();
    for (int s = 128; s > 0; s >>= 1) { if (t < s) red[t] += red[t + s]; __syncthreads(); }
    if (t < 256) Vv[t] = t1 / fmaxf(sqrtf(red[0]), 1e-12f);
    __syncthreads();

    {
        const int o = t & 255, ich = t >> 8;
        float q = 0.f;
        if (o < O) {
            const float4* Wr = (const float4*)(W + (size_t)o * 256 + ich * 64);
            const float4* Vr = (const float4*)(&Vv[ich * 64]);
#pragma unroll
            for (int j = 0; j < 16; ++j) {
                const float4 w = Wr[j]; const float4 v = Vr[j];
                q += w.x * v.x + w.y * v.y + w.z * v.z + w.w * v.w;
            }
        }
        par[ich][o] = q;
    }
    __syncthreads();
    if (t < 256) {
        const float t2 = par[0][t] + par[1][t] + par[2][t] + par[3][t];
        red[t] = t2 * t2;
    }
    __syncthreads();
    for (int s = 128; s > 0; s >>= 1) { if (t < s) red[t] += red[t + s]; __syncthreads(); }
    if (t == 0) {
        const float s2 = red[0];
        sig[which] = fmaxf(sqrtf(s2), 1e-12f) / s2;   // 1/sigma
    }

    // ---- W -> bf16 hi/lo, A-fragment-packed ----
    const int nElem = O * 256;
    const int gbase = (which == 0) ? 0 : (which == 1 ? 32 : 64);  // row base
    for (int i = t; i < nElem; i += 1024) {
        const int o = i >> 8, ci = i & 255;
        const int g = gbase + o;
        const int idx = ((g >> 4) * 8 + (ci >> 5)) * 512 + (g & 15) * 32 + (ci & 31);
        const float f = W[i];
        const u16 h = f2bf(f);
        wh[idx] = h;
        wl[idx] = f2bf(f - bf2f(h));
    }
}

// ---------------------------------------------------------------------------
// Kernel 2: all projections as one MFMA GEMM.  grid (64 n-tiles, 4 b),
// 512 thr (8 waves).  Wave = (nch = wave&3, cohalf = wave>>2).
// A-operands (weights) loaded from fragment-packed global: 1 KB/instr,
// fully coalesced.  x staged fp32 via global_load_lds, column-gathered
// into hi/lo B-frags.  3 MFMAs per K-chunk (wl*xl dropped).
// ---------------------------------------------------------------------------
__global__ __launch_bounds__(512) void k_proj(
    const float* __restrict__ x,
    const u16* __restrict__ wh, const u16* __restrict__ wl,
    const float* __restrict__ fb, const float* __restrict__ gb,
    const float* __restrict__ hb, const float* __restrict__ sig,
    u16* __restrict__ Kc, u16* __restrict__ Qc, u16* __restrict__ Vb)
{
    __shared__ __align__(16) float xs[256][64];  // 64 KB
    __shared__ float bLDS[320];

    const int t = threadIdx.x;
    const int wave = t >> 6, lane = t & 63;
    const int quad = lane >> 4, l15 = lane & 15;
    const int b = blockIdx.y;
    const int n0 = blockIdx.x * 64;
    const int nch = wave & 3, cohalf = wave >> 2;

    // stage x tile [256 ci][64 n]
    {
        const int r4i = lane >> 4, c16 = lane & 15;
        const float* xg = x + (size_t)b * kCHW + (size_t)r4i * kHW + n0 + c16 * 4;
#pragma unroll
        for (int j = 0; j < 8; ++j) {
            const int cibase = (wave * 8 + j) * 4;
            __builtin_amdgcn_global_load_lds(
                (const __attribute__((address_space(1))) void*)(xg + (size_t)cibase * kHW),
                (__attribute__((address_space(3))) void*)&xs[cibase][0], 16, 0, 0);
        }
    }
    if (t < 320) bLDS[t] = (t < 32) ? fb[t] : (t < 64) ? gb[t - 32] : hb[t - 64];
    __syncthreads();

    // B-frags (x) hi/lo for 8 ci-slices; lane = col n
    const int n = nch * 16 + l15;
    bf16x8 bh[8], bl[8];
#pragma unroll
    for (int s = 0; s < 8; ++s) {
        union { u16 a[8]; bf16x8 v; } H, L;
#pragma unroll
        for (int j = 0; j < 8; ++j) {
            const float v = xs[s * 32 + quad * 8 + j][n];
            const u16 h = f2bf(v);
            H.a[j] = h; L.a[j] = f2bf(v - bf2f(h));
        }
        bh[s] = H.v; bl[s] = L.v;
    }

    // A-frag lane base into packed layout
    const u16* whp = wh + l15 * 32 + quad * 8;
    const u16* wlp = wl + l15 * 32 + quad * 8;

    f32x4 acc[10] = {};
#pragma unroll
    for (int c = 0; c < 10; ++c) {
        const size_t base = (size_t)(cohalf * 10 + c) * 4096;
#pragma unroll
        for (int s = 0; s < 8; ++s) {
            const bf16x8 ah = *(const bf16x8*)(whp + base + s * 512);
            const bf16x8 al = *(const bf16x8*)(wlp + base + s * 512);
            acc[c] = __builtin_amdgcn_mfma_f32_16x16x32_bf16(ah, bh[s], acc[c], 0, 0, 0);
            acc[c] = __builtin_amdgcn_mfma_f32_16x16x32_bf16(ah, bl[s], acc[c], 0, 0, 0);
            acc[c] = __builtin_amdgcn_mfma_f32_16x16x32_bf16(al, bh[s], acc[c], 0, 0, 0);
        }
    }

    const float s0 = sig[0], s1 = sig[1], s2 = sig[2];
#pragma unroll
    for (int c = 0; c < 10; ++c) {
        const int cog0 = (cohalf * 10 + c) * 16;
        const float inv = (cog0 < 32) ? s0 : (cog0 < 64) ? s1 : s2;
#pragma unroll
        for (int r = 0; r < 4; ++r) {
            const int co = cog0 + quad * 4 + r;
            const float v = acc[c][r] * inv + bLDS[co];
            if (co < 64) {
                u16* H = (co < 32) ? Kc : Qc;
                const int d = co & 31;
                const u16 h = f2bf(v);
                const u16 l = f2bf(v - bf2f(h));
                const size_t off = (size_t)(b * kHW + n0 + n) * 64;
                H[off + d] = h;
                H[off + 32 + d] = l;
            } else {
                Vb[((size_t)b * kC + (co - 64)) * kHW + n0 + n] = f2bf(v);
            }
        }
    }
}

// ---------------------------------------------------------------------------
// Kernel 3: flash attention v8, 4-way split-K.  grid 1024 (XCD-swizzled;
// id>>8 = key-quarter), 512 thr (8 waves).  __launch_bounds__(512,4):
// VGPR=64 (measured in v6, NO spill); 64 VGPR = the 8-wave/SIMD boundary,
// so HW schedules 4 blocks/CU without forcing the allocator below 64.
// Per block: 64 rows x 1024 keys (16 tiles).
// ---------------------------------------------------------------------------
__global__ __launch_bounds__(512, 4) void k_attn(
    const u16* __restrict__ Kc, const u16* __restrict__ Qc,
    const u16* __restrict__ Vb,
    u16* __restrict__ Op, float2* __restrict__ St)
{
    __shared__ __align__(16) u16 Qt[2][4096];   // 16 KB
    __shared__ __align__(16) u16 Pt[4096];      // 8 KB
    __shared__ float2 stLDS[8][16];
    __shared__ float aLDS[64];

    const int t = threadIdx.x;
    const int wave = t >> 6, lane = t & 63;
    const int quad = lane >> 4, l15 = lane & 15;
    const int sg = wave >> 1, half = wave & 1;

    const int id = blockIdx.x;
    const int xcd = id & 7;
    const int b = xcd >> 1;
    const int nb0 = ((xcd & 1) * 32 + ((id >> 3) & 31)) * 64;
    const int mh = id >> 8;                    // key-quarter (0..3)
    const int mt0 = mh * 16, mt1 = mt0 + 16;

    const u16* Kb  = Kc + (size_t)b * kHW * 64;
    const u16* Qb  = Qc + (size_t)b * kHW * 64;
    const u16* Vbb = Vb + (size_t)b * kC * kHW;

    const size_t krow = (size_t)(nb0 + sg * 16 + l15) * 64 + (size_t)quad * 8;
    const bf16x8 kh = *(const bf16x8*)(Kb + krow);
    const bf16x8 kl = *(const bf16x8*)(Kb + krow + 32);

    const u16* vrow[2];
#pragma unroll
    for (int ct = 0; ct < 2; ++ct)
        vrow[ct] = Vbb + (size_t)(wave * 32 + ct * 16 + l15) * kHW + quad * 8;

    const int qs_row = lane >> 3, qs_ch = lane & 7;

    f32x4 O[8] = {};
    float mrow = -1e30f, lrow = 0.f;
    bf16x8 vc[4], vn[4];

    // ---- prologue ----
    {
        const int rloc = wave * 8 + qs_row;
        __builtin_amdgcn_global_load_lds(
            (const __attribute__((address_space(1))) void*)
                (Qb + (size_t)(mt0 * 64 + rloc) * 64 + ((qs_ch ^ (rloc & 7)) << 3)),
            (__attribute__((address_space(3))) void*)&Qt[0][wave * 512], 16, 0, 0);
    }
#pragma unroll
    for (int ct = 0; ct < 2; ++ct)
#pragma unroll
        for (int ks = 0; ks < 2; ++ks)
            vc[ct * 2 + ks] = *(const bf16x8*)(vrow[ct] + mt0 * 64 + ks * 32);

    for (int mt = mt0; mt < mt1; ++mt) {
        const int cur = mt & 1;
        const int m0 = mt * 64;

        __syncthreads();   // B1: Qt[cur] ready

        if (mt < mt1 - 1) {
            const int m0n = m0 + 64;
            const int rloc = wave * 8 + qs_row;
            __builtin_amdgcn_global_load_lds(
                (const __attribute__((address_space(1))) void*)
                    (Qb + (size_t)(m0n + rloc) * 64 + ((qs_ch ^ (rloc & 7)) << 3)),
                (__attribute__((address_space(3))) void*)&Qt[cur ^ 1][wave * 512], 16, 0, 0);
        }
        const int m0v = (mt < mt1 - 1) ? m0 + 64 : m0;
#pragma unroll
        for (int ct = 0; ct < 2; ++ct)
#pragma unroll
            for (int ks = 0; ks < 2; ++ks)
                vn[ct * 2 + ks] = *(const bf16x8*)(vrow[ct] + m0v + ks * 32);

        // ---- scores for this wave's m-half ----
        f32x4 s[2];
#pragma unroll
        for (int mi2 = 0; mi2 < 2; ++mi2) {
            const int mi = half * 2 + mi2;
            const int rbase = (mi * 16 + l15) * 64;
            const bf16x8 qhv = *(const bf16x8*)&Qt[cur][rbase + ((quad       ^ (l15 & 7)) << 3)];
            const bf16x8 qlv = *(const bf16x8*)&Qt[cur][rbase + (((quad + 4) ^ (l15 & 7)) << 3)];
            f32x4 a = { 0.f, 0.f, 0.f, 0.f };
            a = __builtin_amdgcn_mfma_f32_16x16x32_bf16(qhv, kl, a, 0, 0, 0);
            a = __builtin_amdgcn_mfma_f32_16x16x32_bf16(qlv, kh, a, 0, 0, 0);
            a = __builtin_amdgcn_mfma_f32_16x16x32_bf16(qhv, kh, a, 0, 0, 0);
            s[mi2] = a;
        }

        // ---- wave-local stats ----
        float lm = s[0][0];
#pragma unroll
        for (int mi2 = 0; mi2 < 2; ++mi2)
#pragma unroll
            for (int r = 0; r < 4; ++r) lm = fmaxf(lm, s[mi2][r]);
        lm = fmaxf(lm, __shfl_xor(lm, 16));
        lm = fmaxf(lm, __shfl_xor(lm, 32));
        float ls = 0.f;
#pragma unroll
        for (int mi2 = 0; mi2 < 2; ++mi2)
#pragma unroll
            for (int r = 0; r < 4; ++r) {
                const float p = __expf(s[mi2][r] - lm);
                s[mi2][r] = p;
                ls += p;
            }
        ls += __shfl_xor(ls, 16);
        ls += __shfl_xor(ls, 32);
        if (lane < 16) stLDS[wave][l15] = make_float2(lm, ls);

        asm volatile("s_waitcnt lgkmcnt(0)\n\ts_barrier" ::: "memory");  // Bstat

        const float2 o2 = stLDS[wave ^ 1][l15];
        const float mnew = fmaxf(mrow, fmaxf(lm, o2.x));
        const float alpha = __expf(mrow - mnew);
        const float bm = __expf(lm - mnew);
        lrow = lrow * alpha + ls * bm + o2.y * __expf(o2.x - mnew);
        mrow = mnew;

        // ---- pack P (scaled by bm), write alpha ----
        {
            const int prow = sg * 16 + l15;
#pragma unroll
            for (int mi2 = 0; mi2 < 2; ++mi2) {
                const float p0 = s[mi2][0] * bm, p1 = s[mi2][1] * bm;
                const float p2 = s[mi2][2] * bm, p3 = s[mi2][3] * bm;
                const unsigned d0 = __builtin_amdgcn_perm(
                    __float_as_uint(p1), __float_as_uint(p0), 0x07060302u);
                const unsigned d1 = __builtin_amdgcn_perm(
                    __float_as_uint(p3), __float_as_uint(p2), 0x07060302u);
                const int mi = half * 2 + mi2;
                const int chunk = 2 * mi + (quad >> 1);
                const int off = prow * 64 + ((chunk ^ (l15 & 7)) << 3) + (quad & 1) * 4;
                *(uint2*)(Pt + off) = make_uint2(d0, d1);
            }
            if (half == 0 && lane < 16) aLDS[sg * 16 + l15] = alpha;
        }

        asm volatile("s_waitcnt lgkmcnt(0)\n\ts_barrier" ::: "memory");  // BP

        // ---- rescale O ----
#pragma unroll
        for (int rg = 0; rg < 4; ++rg) {
            const float4 af = *(const float4*)&aLDS[rg * 16 + quad * 4];
#pragma unroll
            for (int ct = 0; ct < 2; ++ct) {
                O[rg * 2 + ct][0] *= af.x;
                O[rg * 2 + ct][1] *= af.y;
                O[rg * 2 + ct][2] *= af.z;
                O[rg * 2 + ct][3] *= af.w;
            }
        }

        // ---- PV ----
#pragma unroll
        for (int ks = 0; ks < 2; ++ks) {
#pragma unroll
            for (int rg = 0; rg < 4; ++rg) {
                const bf16x8 pa = *(const bf16x8*)&Pt[(rg * 16 + l15) * 64
                                     + (((ks * 4 + quad) ^ (l15 & 7)) << 3)];
#pragma unroll
                for (int ct = 0; ct < 2; ++ct)
                    O[rg * 2 + ct] = __builtin_amdgcn_mfma_f32_16x16x32_bf16(
                        pa, vc[ct * 2 + ks], O[rg * 2 + ct], 0, 0, 0);
            }
        }

#pragma unroll
        for (int i = 0; i < 4; ++i) vc[i] = vn[i];
    }

    // ---- epilogue: bf16 partial O + stats ----
    if (half == 0 && lane < 16)
        St[(size_t)(mh * 4 + b) * kHW + nb0 + sg * 16 + l15] = make_float2(mrow, lrow);

    u16* Opb = Op + (size_t)(mh * 4 + b) * kHW * 256;
#pragma unroll
    for (int rg = 0; rg < 4; ++rg) {
#pragma unroll
        for (int ct = 0; ct < 2; ++ct) {
#pragma unroll
            for (int r = 0; r < 4; ++r) {
                const int nn = nb0 + rg * 16 + quad * 4 + r;
                const int c = wave * 32 + ct * 16 + l15;
                Opb[(size_t)nn * 256 + c] = f2bf(O[rg * 2 + ct][r]);
            }
        }
    }
}

// ---------------------------------------------------------------------------
// Kernel 4: merge the four key-quarters + epilogue.  grid 2048 x 256 thr,
// 8 channels per thread, fully coalesced.
// ---------------------------------------------------------------------------
__global__ __launch_bounds__(256) void k_merge(
    const float* __restrict__ x, const float* __restrict__ gamma,
    const u16* __restrict__ Op, const float2* __restrict__ St,
    float* __restrict__ out)
{
    const int tid = blockIdx.x * 256 + threadIdx.x;
    const int cg = tid & 31;
    const int n  = (tid >> 5) & 4095;
    const int b  = tid >> 17;
    const int c0 = cg * 8;

    float2 st[4];
#pragma unroll
    for (int q = 0; q < 4; ++q) st[q] = St[(size_t)(q * 4 + b) * kHW + n];
    float M = st[0].x;
#pragma unroll
    for (int q = 1; q < 4; ++q) M = fmaxf(M, st[q].x);
    float w[4], L = 0.f;
#pragma unroll
    for (int q = 0; q < 4; ++q) { w[q] = __expf(st[q].x - M); L += st[q].y * w[q]; }
    const float invL = 1.f / L;
#pragma unroll
    for (int q = 0; q < 4; ++q) w[q] *= invL;
    const float g = gamma[0];

    const size_t base = ((size_t)b * kHW + n) * 256 + c0;
    uint4 A[4];
#pragma unroll
    for (int q = 0; q < 4; ++q)
        A[q] = *(const uint4*)(Op + base + (size_t)q * 4 * kHW * 256);
    const float4 x0 = *(const float4*)(x + base);
    const float4 x1 = *(const float4*)(x + base + 4);

    float o[8];
#pragma unroll
    for (int j = 0; j < 8; ++j) {
        float acc = 0.f;
#pragma unroll
        for (int q = 0; q < 4; ++q) {
            const unsigned word = (j >> 1) == 0 ? A[q].x : (j >> 1) == 1 ? A[q].y
                                 : (j >> 1) == 2 ? A[q].z : A[q].w;
            acc += bf2f((u16)(word >> ((j & 1) * 16))) * w[q];
        }
        o[j] = acc;
    }
    float4 r0, r1;
    r0.x = g * o[0] + x0.x; r0.y = g * o[1] + x0.y;
    r0.z = g * o[2] + x0.z; r0.w = g * o[3] + x0.w;
    r1.x = g * o[4] + x1.x; r1.y = g * o[5] + x1.y;
    r1.z = g * o[6] + x1.z; r1.w = g * o[7] + x1.w;
    *(float4*)(out + base)     = r0;
    *(float4*)(out + base + 4) = r1;
}

// ---------------------------------------------------------------------------
extern "C" void kernel_launch(void* const* d_in, const int* in_sizes, int n_in,
                              void* d_out, int out_size, void* d_ws, size_t ws_size,
                              hipStream_t stream)
{
    const float* x     = (const float*)d_in[0];
    const float* fw    = (const float*)d_in[1];
    const float* fb    = (const float*)d_in[2];
    const float* fu    = (const float*)d_in[3];
    const float* gw    = (const float*)d_in[4];
    const float* gb    = (const float*)d_in[5];
    const float* gu    = (const float*)d_in[6];
    const float* hww   = (const float*)d_in[7];
    const float* hb    = (const float*)d_in[8];
    const float* hu    = (const float*)d_in[9];
    const float* gamma = (const float*)d_in[10];
    float* out = (float*)d_out;

    char* ws = (char*)d_ws;
    float* sig = (float*)ws;                        // 3 floats
    u16* wh = (u16*)(ws + 1024);                    // packed 320x256 bf16 hi
    u16* wl = wh + 320 * 256;                       // packed lo
    u16* Kc = (u16*)(ws + (1u << 20));              // 2 MB
    u16* Qc = (u16*)(ws + (3u << 20));              // 2 MB
    u16* Vb = (u16*)(ws + (5u << 20));              // 8 MB
    u16* Op = (u16*)(ws + (16u << 20));             // 32 MB: [4][4][4096][256] bf16
    float2* St = (float2*)(ws + (48u << 20));       // 512 KB: [4][4][4096]

    k_sigma<<<dim3(3), dim3(1024), 0, stream>>>(fw, fu, gw, gu, hww, hu, sig, wh, wl);
    k_proj<<<dim3(64, 4), dim3(512), 0, stream>>>(x, wh, wl, fb, gb, hb, sig,
                                                  Kc, Qc, Vb);
    k_attn<<<dim3(1024), dim3(512), 0, stream>>>(Kc, Qc, Vb, Op, St);
    k_merge<<<dim3(2048), dim3(256), 0, stream>>>(x, gamma, Op, St, out);
}